// Round 8
// baseline (13307.767 us; speedup 1.0000x reference)
//
#include <hip/hip_runtime.h>
#include <hip/hip_bf16.h>
#include <cmath>

typedef __attribute__((ext_vector_type(8))) short bf16x8;
typedef __attribute__((ext_vector_type(4))) float f32x4;
typedef unsigned int u32;

#define DEVI __device__ __forceinline__

DEVI float sigf(float x) { return 1.0f / (1.0f + __expf(-x)); }

// async global->LDS, 16B per lane. LDS dest must be wave-uniform base (HW adds lane*16).
typedef const __attribute__((address_space(1))) u32* gas_t;
typedef __attribute__((address_space(3))) u32* las_t;
DEVI void g2l16(const void* g, void* l) {
  __builtin_amdgcn_global_load_lds((gas_t)g, (las_t)l, 16, 0, 0);
}

// ---- problem constants
#define BATCH 1024
#define CODE  2048
#define RNN   512
#define NG    2048      // 4*RNN
#define TSTEPS 128
#define K1K   2560      // CODE + RNN
#define K2K   1024
#define K3K   512

#define BUFSZ 16384     // one BK=64 B-tile stage: 128 rows x 128B

// ---------------------------------------------------------------------------
// prologue kernels (run every launch; d_ws is re-poisoned before each launch)
// ---------------------------------------------------------------------------

__global__ void conv_w1(const float* __restrict__ w_ih1, const float* __restrict__ w_hh1,
                        __hip_bfloat16* __restrict__ W1T) {
  int np = blockIdx.x;                       // 0..2047, gate-interleaved: np = 4u+g
  int co = (np & 3) * RNN + (np >> 2);       // original gate column
  for (int k = threadIdx.x; k < K1K; k += 256) {
    float v = (k < CODE) ? w_ih1[(size_t)k * NG + co]
                         : w_hh1[(size_t)(k - CODE) * NG + co];
    W1T[(size_t)np * K1K + k] = __float2bfloat16(v);
  }
}

__global__ void conv_w2(const float* __restrict__ w_ih2, const float* __restrict__ w_hh2,
                        __hip_bfloat16* __restrict__ W2T) {
  int np = blockIdx.x;
  int co = (np & 3) * RNN + (np >> 2);
  for (int k = threadIdx.x; k < K2K; k += 256) {
    float v = (k < RNN) ? w_ih2[(size_t)k * NG + co]
                        : w_hh2[(size_t)(k - RNN) * NG + co];
    W2T[(size_t)np * K2K + k] = __float2bfloat16(v);
  }
}

// WoT[n][k], n<2048 (att only; heads handled separately)
__global__ void conv_wo(const float* __restrict__ w_att, __hip_bfloat16* __restrict__ WoT) {
  int n = blockIdx.x;  // 0..2047
  for (int k = threadIdx.x; k < K3K; k += 256)
    WoT[(size_t)n * K3K + k] = __float2bfloat16(w_att[(size_t)k * CODE + n]);
}

__global__ void conv_b(const float* b_ih1, const float* b_hh1,
                       const float* b_ih2, const float* b_hh2,
                       const float* b_att,
                       float* b1p, float* b2p, float* bo) {
  int i = blockIdx.x * 256 + threadIdx.x;
  if (i < NG) {
    int co = (i & 3) * RNN + (i >> 2);
    b1p[i] = b_ih1[co] + b_hh1[co];
    b2p[i] = b_ih2[co] + b_hh2[co];
    bo[i] = b_att[i];   // natural order, i < 2048 == NG
  }
}

// zero hbuf0(2MB)+c1(2MB)+c2(2MB) contiguous + the h1 strip of xbuf
__global__ void init_zero(char* __restrict__ zb, char* __restrict__ xb) {
  int idx = blockIdx.x * 256 + threadIdx.x;       // 262144 threads
  f32x4 z = {0.f, 0.f, 0.f, 0.f};
  for (int i = idx; i < 393216; i += 262144) *(f32x4*)(zb + (size_t)i * 16) = z;
  for (int i = idx; i < 65536; i += 262144) {
    int row = i >> 6, j = i & 63;
    *(f32x4*)(xb + (size_t)row * (K1K * 2) + CODE * 2 + (size_t)j * 16) = z;
  }
}

// idea = tanh(latent @ w_unpack + b); also xbuf[:,0:2048] = idea (att0 = 1)
__global__ void idea_kernel(const float* __restrict__ latent, const float* __restrict__ w,
                            const float* __restrict__ b,
                            __hip_bfloat16* __restrict__ idea_bf,
                            __hip_bfloat16* __restrict__ x_bf) {
  int idx = blockIdx.x * 256 + threadIdx.x;       // 2M = 1024*2048
  int bi = idx >> 11, j = idx & 2047;
  const float* lr = latent + bi * 128;
  float s = b[j];
#pragma unroll 8
  for (int k = 0; k < 128; ++k) s = fmaf(lr[k], w[(size_t)k * CODE + j], s);
  __hip_bfloat16 h = __float2bfloat16(tanhf(s));
  idea_bf[idx] = h;
  x_bf[(size_t)bi * K1K + j] = h;
}

// ---- shared GEMM inner-loop fragments (8 waves, wave tile 32x32, BK=64) ----
// B staged in LDS: B[128][128B] linear (involution: LDS[r*128+q] holds global
// (r, q ^ ((r&7)<<4))); 16 1KB chunks, 2/wave.
// A fragments load DIRECTLY from global (L1-resident tile; 4-way wave reuse).

#define STAGE(KO, DST)                                                        \
  _Pragma("unroll") for (int j = 0; j < 2; ++j)                               \
      g2l16(gp[j] + (KO), (DST) + ldsc[j]);

#define COMPUTE(SB, KO)                                                       \
  __builtin_amdgcn_s_setprio(1);                                              \
  _Pragma("unroll") for (int kk = 0; kk < 2; ++kk) {                          \
    bf16x8 av[2], bv[2];                                                      \
    _Pragma("unroll") for (int fm = 0; fm < 2; ++fm)                          \
        av[fm] = *(const bf16x8*)(ap[fm] + (KO) + kk * 64);                   \
    _Pragma("unroll") for (int fn = 0; fn < 2; ++fn)                          \
        bv[fn] = *(const bf16x8*)((SB) + boff[fn][kk]);                       \
    _Pragma("unroll") for (int fm = 0; fm < 2; ++fm)                          \
      _Pragma("unroll") for (int fn = 0; fn < 2; ++fn)                        \
        acc[fm][fn] = __builtin_amdgcn_mfma_f32_16x16x32_bf16(                \
            av[fm], bv[fn], acc[fm][fn], 0, 0, 0);                            \
  }                                                                           \
  __builtin_amdgcn_s_setprio(0);

#define WAITB(N)                                                              \
  asm volatile("s_waitcnt vmcnt(" #N ")" ::: "memory");                       \
  __builtin_amdgcn_s_barrier();                                               \
  asm volatile("" ::: "memory");

#define GEMM_SETUP(AB, AKB, BB, BKB)                                          \
  const int lane = tid & 63, wv = tid >> 6;                                   \
  const int rl = lane >> 3;                                                   \
  const int cswz = ((lane & 7) * 16) ^ (rl << 4);                             \
  const char* gp[2]; int ldsc[2];                                             \
  _Pragma("unroll") for (int j = 0; j < 2; ++j) {                             \
    int c = wv * 2 + j;                                                       \
    gp[j] = (BB) + (size_t)(n0 + c * 8 + rl) * (BKB) + cswz;                  \
    ldsc[j] = c * 1024;                                                       \
  }                                                                           \
  const int l16 = lane & 15, lg = lane >> 4;                                  \
  const int wr = wv & 1, wc = wv >> 1;                                        \
  const int xm = (l16 & 7) << 4;                                              \
  const char* ap[2];                                                          \
  _Pragma("unroll") for (int fm = 0; fm < 2; ++fm)                            \
    ap[fm] = (AB) + (size_t)(m0 + wr * 32 + fm * 16 + l16) * (AKB) + lg * 16; \
  int boff[2][2];                                                             \
  _Pragma("unroll") for (int fn = 0; fn < 2; ++fn) {                          \
    int r = wc * 32 + fn * 16 + l16;                                          \
    _Pragma("unroll") for (int kk = 0; kk < 2; ++kk)                          \
      boff[fn][kk] = r * 128 + ((kk * 64 + lg * 16) ^ xm);                    \
  }                                                                           \
  f32x4 z4 = {0.f, 0.f, 0.f, 0.f};                                            \
  f32x4 acc[2][2];                                                            \
  _Pragma("unroll") for (int a = 0; a < 2; ++a)                               \
    _Pragma("unroll") for (int b = 0; b < 2; ++b) acc[a][b] = z4;

#define GEMM_PIPELINE(NK)                                                     \
  STAGE(0, smem);                                                             \
  STAGE(128, smem + BUFSZ);                                                   \
  for (int kt = 0; kt < (NK) - 1; ++kt) {                                     \
    WAITB(2);                                                                 \
    if (kt + 2 < (NK)) {                                                      \
      char* nb = smem + ((kt + 2) % 3) * BUFSZ;                               \
      STAGE((size_t)(kt + 2) * 128, nb);                                      \
    }                                                                         \
    const char* sb = smem + (kt % 3) * BUFSZ;                                 \
    COMPUTE(sb, (size_t)kt * 128);                                            \
  }                                                                           \
  WAITB(0);                                                                   \
  COMPUTE(smem + (((NK) - 1) % 3) * BUFSZ, (size_t)((NK) - 1) * 128);

// ---------------------------------------------------------------------------
// Fused GEMM + LSTM cell. C = A[1024,K] @ BT[2048,K]^T, gate-interleaved N.
// BM=64, BN=128, BK=64; 512 threads = 8 waves (2x4), wave tile 32x32.
// Writes h to hd0 (and hd1 if non-null). HEADS: per-block partial head dots.
// ---------------------------------------------------------------------------
template<bool HEADS>
__global__ void __launch_bounds__(512, 2)
lstm_gemm(const char* __restrict__ Ab, const char* __restrict__ Bb,
          int kb, int nk, const float* __restrict__ bias,
          float* __restrict__ c_state,
          __hip_bfloat16* __restrict__ hd0, int ld0,
          const float* __restrict__ w_ang, const float* __restrict__ w_wid,
          float* __restrict__ partial) {
  __shared__ char smem[3 * BUFSZ];  // 48KB; epilogue reuses 32KB as f32[64][128]
  const int tid = threadIdx.x;
  const int l = blockIdx.x;              // 256 blocks, XCD-swizzled
  const int xcd = l & 7, bi = l >> 3;
  const int n0 = ((xcd << 1) | (bi & 1)) * 128;
  const int m0 = (bi >> 1) * 64;

  GEMM_SETUP(Ab, kb, Bb, kb)
  GEMM_PIPELINE(nk)

  // ---- epilogue: recombine gates in LDS, apply LSTM cell
  __syncthreads();
  float* gsm = (float*)smem;  // [64][128]
#pragma unroll
  for (int fm = 0; fm < 2; ++fm)
#pragma unroll
    for (int fn = 0; fn < 2; ++fn) {
      int col = wc * 32 + fn * 16 + l16;
#pragma unroll
      for (int j = 0; j < 4; ++j)
        gsm[(wr * 32 + fm * 16 + lg * 4 + j) * 128 + col] = acc[fm][fn][j];
    }
  __syncthreads();
#pragma unroll
  for (int i = 0; i < 4; ++i) {
    int p = tid + i * 512;            // 2048 = 64 rows x 32 units
    int unit = p & 31, row = p >> 5;
    f32x4 g = *(const f32x4*)(gsm + row * 128 + unit * 4);
    f32x4 bb = *(const f32x4*)(bias + n0 + unit * 4);
    float ig = sigf(g.x + bb.x);
    float fg = sigf(g.y + bb.y);
    float gg = tanhf(g.z + bb.z);
    float og = sigf(g.w + bb.w);
    int grow = m0 + row, gu = (n0 >> 2) + unit;
    float cold = c_state[grow * RNN + gu];
    float cn = fg * cold + ig * gg;
    c_state[grow * RNN + gu] = cn;
    float h = og * tanhf(cn);
    hd0[(size_t)grow * ld0 + gu] = __float2bfloat16(h);
    if (HEADS) {
      // partial head dots: 32 consecutive tids share this row
      float pa = h * w_ang[gu], pw = h * w_wid[gu];
#pragma unroll
      for (int m = 1; m < 32; m <<= 1) {
        pa += __shfl_xor(pa, m);
        pw += __shfl_xor(pw, m);
      }
      if ((tid & 31) == 0) {
        float* pp = partial + ((size_t)(n0 >> 7) * 1024 + grow) * 2;
        pp[0] = pa; pp[1] = pw;
      }
    }
  }
}

// ---------------------------------------------------------------------------
// K3: att = sigmoid(h2 @ WoT^T); xbuf[:, :2048] = idea*att.
// Also: h1 strip copy (spread over all 256 blocks, 4KB each) and, for the 16
// n0==0 blocks, finalize heads from K2's partials -> out[b,t,:].
// BM=64, BN=128, grid 256 (16x16 via XCD swizzle).
// ---------------------------------------------------------------------------
__global__ void __launch_bounds__(512, 2)
att_gemm(const char* __restrict__ Ab, int akb,      // h2 region, row stride bytes
         const char* __restrict__ Bb, int bkb,      // WoT
         const float* __restrict__ bo,
         const __hip_bfloat16* __restrict__ idea_bf,
         __hip_bfloat16* __restrict__ xbuf,
         const char* __restrict__ h1src,            // hbuf[t&1] (h1 cols 0..511)
         const float* __restrict__ partial,
         const float* __restrict__ b_ang, const float* __restrict__ b_wid,
         float* __restrict__ out, int t) {
  __shared__ char smem[3 * BUFSZ];
  const int tid = threadIdx.x;
  const int l = blockIdx.x;
  const int xcd = l & 7, bi = l >> 3;
  const int n0 = ((xcd << 1) | (bi & 1)) * 128;
  const int m0 = (bi >> 1) * 64;
  const int j16 = n0 >> 7;

  // h1 strip copy for next step's K1 input: rows m0..m0+63, 64B of cols
  if (tid < 256) {
    int row = m0 + (tid >> 2), cb = (tid & 3) * 16;
    *(f32x4*)((char*)xbuf + (size_t)row * (K1K * 2) + CODE * 2 + j16 * 64 + cb) =
        *(const f32x4*)(h1src + (size_t)row * 2048 + j16 * 64 + cb);
  }

  GEMM_SETUP(Ab, akb, Bb, bkb)
  const int nk = K3K / 64;  // 8
  GEMM_PIPELINE(nk)

  // per-lane epilogue: all cols are att
#pragma unroll
  for (int fn = 0; fn < 2; ++fn) {
    int col = n0 + wc * 32 + fn * 16 + l16;
    float bia = bo[col];
#pragma unroll
    for (int fm = 0; fm < 2; ++fm)
#pragma unroll
      for (int j = 0; j < 4; ++j) {
        int row = m0 + wr * 32 + fm * 16 + lg * 4 + j;
        float a = sigf(acc[fm][fn][j] + bia);
        float id = __bfloat162float(idea_bf[(size_t)row * CODE + col]);
        xbuf[(size_t)row * K1K + col] = __float2bfloat16(id * a);
      }
  }

  // heads finalize: 16 blocks (n0==0), 64 rows x 2 outputs each
  if (n0 == 0 && tid < 128) {
    int row = m0 + (tid >> 1), g = tid & 1;
    float s = g ? b_wid[0] : b_ang[0];
#pragma unroll
    for (int j = 0; j < 16; ++j) s += partial[((size_t)j * 1024 + row) * 2 + g];
    out[(size_t)row * (TSTEPS * 2) + t * 2 + g] = g ? sigf(s) : tanhf(s);
  }
}

// ---------------------------------------------------------------------------
extern "C" void kernel_launch(void* const* d_in, const int* in_sizes, int n_in,
                              void* d_out, int out_size, void* d_ws, size_t ws_size,
                              hipStream_t stream) {
  const float* latent = (const float*)d_in[0];
  const float* w_unp  = (const float*)d_in[2];
  const float* b_unp  = (const float*)d_in[3];
  const float* w_ih1  = (const float*)d_in[4];
  const float* w_hh1  = (const float*)d_in[5];
  const float* b_ih1  = (const float*)d_in[6];
  const float* b_hh1  = (const float*)d_in[7];
  const float* w_ih2  = (const float*)d_in[8];
  const float* w_hh2  = (const float*)d_in[9];
  const float* b_ih2  = (const float*)d_in[10];
  const float* b_hh2  = (const float*)d_in[11];
  const float* w_att  = (const float*)d_in[12];
  const float* b_att  = (const float*)d_in[13];
  const float* w_wid  = (const float*)d_in[14];
  const float* b_wid  = (const float*)d_in[15];
  const float* w_ang  = (const float*)d_in[16];
  const float* b_ang  = (const float*)d_in[17];
  float* out = (float*)d_out;

  char* ws = (char*)d_ws;
  __hip_bfloat16* W1T  = (__hip_bfloat16*)(ws + 0);          // 2048 x 2560
  __hip_bfloat16* W2T  = (__hip_bfloat16*)(ws + 10485760);   // 2048 x 1024
  __hip_bfloat16* WoT  = (__hip_bfloat16*)(ws + 14680064);   // 2048 x 512
  float* b1p           = (float*)(ws + 16777216);            // 2048
  float* b2p           = (float*)(ws + 16785408);            // 2048
  float* bo            = (float*)(ws + 16793600);            // 2048
  __hip_bfloat16* idea = (__hip_bfloat16*)(ws + 16801792);   // 1024 x 2048
  __hip_bfloat16* xbuf = (__hip_bfloat16*)(ws + 20996096);   // 1024 x 2560 [idea*att | h1]
  __hip_bfloat16* hb0  = (__hip_bfloat16*)(ws + 26238976);   // 1024 x 1024 [h1|h2]
  float* c1            = (float*)(ws + 28336128);            // 1024 x 512
  float* c2            = (float*)(ws + 30433280);            // 1024 x 512
  __hip_bfloat16* hb1  = (__hip_bfloat16*)(ws + 32530432);   // 1024 x 1024
  float* partial       = (float*)(ws + 34627584);            // 16 x 1024 x 2

  __hip_bfloat16* hbuf[2] = {hb0, hb1};

  conv_w1<<<2048, 256, 0, stream>>>(w_ih1, w_hh1, W1T);
  conv_w2<<<2048, 256, 0, stream>>>(w_ih2, w_hh2, W2T);
  conv_wo<<<2048, 256, 0, stream>>>(w_att, WoT);
  conv_b<<<8, 256, 0, stream>>>(b_ih1, b_hh1, b_ih2, b_hh2, b_att, b1p, b2p, bo);
  init_zero<<<1024, 256, 0, stream>>>(ws + 26238976, (char*)xbuf);
  idea_kernel<<<8192, 256, 0, stream>>>(latent, w_unp, b_unp, idea, xbuf);

  for (int t = 0; t < TSTEPS; ++t) {
    __hip_bfloat16* hc = hbuf[t & 1];        // [h1(t) | h2(t-1)] for K2
    __hip_bfloat16* hn = hbuf[(t + 1) & 1];  // next-step buffer
    // K1: gates1 = xbuf @ W1 ; cell -> c1, h1 -> hc[:,0:512]
    lstm_gemm<false><<<256, 512, 0, stream>>>(
        (const char*)xbuf, (const char*)W1T, K1K * 2, K1K / 64, b1p, c1,
        hc, 1024, nullptr, nullptr, nullptr);
    // K2: gates2 = hc @ W2 ; cell -> c2, h2 -> hn[:,512:1024]; head partials
    lstm_gemm<true><<<256, 512, 0, stream>>>(
        (const char*)hc, (const char*)W2T, K2K * 2, K2K / 64, b2p, c2,
        hn + RNN, 1024, w_ang, w_wid, partial);
    // K3: att from h2 (hn cols 512:1024); writes xbuf[:, :2048]; h1 strip copy
    // (hc cols 0:512 -> xbuf cols 2048:2560); heads finalize -> out
    att_gemm<<<256, 512, 0, stream>>>(
        (const char*)hn + 1024, 2048, (const char*)WoT, 1024,
        bo, idea, xbuf, (const char*)hc, partial, b_ang, b_wid, out, t);
  }
}

// Round 9
// 7229.253 us; speedup vs baseline: 1.8408x; 1.8408x over previous
//
#include <hip/hip_runtime.h>
#include <hip/hip_bf16.h>
#include <cmath>

typedef __attribute__((ext_vector_type(8))) short bf16x8;
typedef __attribute__((ext_vector_type(4))) float f32x4;
typedef unsigned int u32;

#define DEVI __device__ __forceinline__

DEVI float sigf(float x) { return 1.0f / (1.0f + __expf(-x)); }

// async global->LDS, 16B per lane. LDS dest must be wave-uniform base (HW adds lane*16).
typedef const __attribute__((address_space(1))) u32* gas_t;
typedef __attribute__((address_space(3))) u32* las_t;
DEVI void g2l16(const void* g, void* l) {
  __builtin_amdgcn_global_load_lds((gas_t)g, (las_t)l, 16, 0, 0);
}

// ---- problem constants
#define BATCH 1024
#define CODE  2048
#define RNN   512
#define NG    2048      // 4*RNN
#define TSTEPS 128
#define K1K   2560      // CODE + RNN
#define K2K   1024
#define K3K   512

#define BUFSZ 32768     // one BK=64 tile: A[128][128B] + B[128][128B]

// ---------------------------------------------------------------------------
// prologue kernels (run every launch; d_ws is re-poisoned before each launch)
// ---------------------------------------------------------------------------

__global__ void conv_w1(const float* __restrict__ w_ih1, const float* __restrict__ w_hh1,
                        __hip_bfloat16* __restrict__ W1T) {
  int np = blockIdx.x;                       // 0..2047, gate-interleaved: np = 4u+g
  int co = (np & 3) * RNN + (np >> 2);       // original gate column
  for (int k = threadIdx.x; k < K1K; k += 256) {
    float v = (k < CODE) ? w_ih1[(size_t)k * NG + co]
                         : w_hh1[(size_t)(k - CODE) * NG + co];
    W1T[(size_t)np * K1K + k] = __float2bfloat16(v);
  }
}

__global__ void conv_w2(const float* __restrict__ w_ih2, const float* __restrict__ w_hh2,
                        __hip_bfloat16* __restrict__ W2T) {
  int np = blockIdx.x;
  int co = (np & 3) * RNN + (np >> 2);
  for (int k = threadIdx.x; k < K2K; k += 256) {
    float v = (k < RNN) ? w_ih2[(size_t)k * NG + co]
                        : w_hh2[(size_t)(k - RNN) * NG + co];
    W2T[(size_t)np * K2K + k] = __float2bfloat16(v);
  }
}

// WoT[n][k], n<2048 (att only; heads handled separately)
__global__ void conv_wo(const float* __restrict__ w_att, __hip_bfloat16* __restrict__ WoT) {
  int n = blockIdx.x;  // 0..2047
  for (int k = threadIdx.x; k < K3K; k += 256)
    WoT[(size_t)n * K3K + k] = __float2bfloat16(w_att[(size_t)k * CODE + n]);
}

__global__ void conv_b(const float* b_ih1, const float* b_hh1,
                       const float* b_ih2, const float* b_hh2,
                       const float* b_att,
                       float* b1p, float* b2p, float* bo) {
  int i = blockIdx.x * 256 + threadIdx.x;
  if (i < NG) {
    int co = (i & 3) * RNN + (i >> 2);
    b1p[i] = b_ih1[co] + b_hh1[co];
    b2p[i] = b_ih2[co] + b_hh2[co];
    bo[i] = b_att[i];   // natural order, i < 2048 == NG
  }
}

// zero hbuf0(2MB)+c1(2MB)+c2(2MB) contiguous + the h1 strip of xbuf
__global__ void init_zero(char* __restrict__ zb, char* __restrict__ xb) {
  int idx = blockIdx.x * 256 + threadIdx.x;       // 262144 threads
  f32x4 z = {0.f, 0.f, 0.f, 0.f};
  for (int i = idx; i < 393216; i += 262144) *(f32x4*)(zb + (size_t)i * 16) = z;
  for (int i = idx; i < 65536; i += 262144) {
    int row = i >> 6, j = i & 63;
    *(f32x4*)(xb + (size_t)row * (K1K * 2) + CODE * 2 + (size_t)j * 16) = z;
  }
}

// idea = tanh(latent @ w_unpack + b); also xbuf[:,0:2048] = idea (att0 = 1)
__global__ void idea_kernel(const float* __restrict__ latent, const float* __restrict__ w,
                            const float* __restrict__ b,
                            __hip_bfloat16* __restrict__ idea_bf,
                            __hip_bfloat16* __restrict__ x_bf) {
  int idx = blockIdx.x * 256 + threadIdx.x;       // 2M = 1024*2048
  int bi = idx >> 11, j = idx & 2047;
  const float* lr = latent + bi * 128;
  float s = b[j];
#pragma unroll 8
  for (int k = 0; k < 128; ++k) s = fmaf(lr[k], w[(size_t)k * CODE + j], s);
  __hip_bfloat16 h = __float2bfloat16(tanhf(s));
  idea_bf[idx] = h;
  x_bf[(size_t)bi * K1K + j] = h;
}

// ---- shared GEMM inner-loop fragments --------------------------------------
// BM=128, BN=128, BK=64; 512 threads = 8 waves (2 row x 4 col), wave tile 64x32.
// LDS buffer: A[128][128B] @0, B[128][128B] @16384 (linear; involution:
// LDS[r*128+q] holds global (r, q ^ ((r&7)<<4))). 32 1KB chunks, 4/wave.
// 2 buffers, depth-1 counted prefetch: STAGE(next) -> vmcnt(4)+barrier ->
// COMPUTE(cur) -> barrier (trailing barrier protects cur buf from next stage).

#define STAGE(KO, DST)                                                        \
  _Pragma("unroll") for (int j = 0; j < 4; ++j)                               \
      g2l16(gp[j] + (KO), (DST) + ldsc[j]);

#define COMPUTE(SB)                                                           \
  __builtin_amdgcn_s_setprio(1);                                              \
  _Pragma("unroll") for (int kk = 0; kk < 2; ++kk) {                          \
    bf16x8 av[4], bv[2];                                                      \
    _Pragma("unroll") for (int fm = 0; fm < 4; ++fm)                          \
        av[fm] = *(const bf16x8*)((SB) + aoff[fm][kk]);                       \
    _Pragma("unroll") for (int fn = 0; fn < 2; ++fn)                          \
        bv[fn] = *(const bf16x8*)((SB) + boff[fn][kk]);                       \
    _Pragma("unroll") for (int fm = 0; fm < 4; ++fm)                          \
      _Pragma("unroll") for (int fn = 0; fn < 2; ++fn)                        \
        acc[fm][fn] = __builtin_amdgcn_mfma_f32_16x16x32_bf16(                \
            av[fm], bv[fn], acc[fm][fn], 0, 0, 0);                            \
  }                                                                           \
  __builtin_amdgcn_s_setprio(0);

#define WAITB(N)                                                              \
  asm volatile("s_waitcnt vmcnt(" #N ")" ::: "memory");                       \
  __builtin_amdgcn_s_barrier();                                               \
  asm volatile("" ::: "memory");

#define GEMM_SETUP(AB, AKB, BB, BKB)                                          \
  const int lane = tid & 63, wv = tid >> 6;                                   \
  const int rl = lane >> 3;                                                   \
  const int cswz = ((lane & 7) * 16) ^ (rl << 4);                             \
  const char* gp[4]; int ldsc[4];                                             \
  _Pragma("unroll") for (int j = 0; j < 4; ++j) {                             \
    int c = wv * 4 + j;                                                       \
    int row = (c < 16) ? (m0 + c * 8 + rl) : (n0 + (c - 16) * 8 + rl);        \
    gp[j] = ((c < 16) ? (AB) : (BB)) +                                        \
            (size_t)row * ((c < 16) ? (AKB) : (BKB)) + cswz;                  \
    ldsc[j] = c * 1024;                                                       \
  }                                                                           \
  const int l16 = lane & 15, lg = lane >> 4;                                  \
  const int wr = wv & 1, wc = wv >> 1;                                        \
  const int xm = (l16 & 7) << 4;                                              \
  int aoff[4][2], boff[2][2];                                                 \
  _Pragma("unroll") for (int fm = 0; fm < 4; ++fm) {                          \
    int r = wr * 64 + fm * 16 + l16;                                          \
    _Pragma("unroll") for (int kk = 0; kk < 2; ++kk)                          \
      aoff[fm][kk] = r * 128 + ((kk * 64 + lg * 16) ^ xm);                    \
  }                                                                           \
  _Pragma("unroll") for (int fn = 0; fn < 2; ++fn) {                          \
    int r = wc * 32 + fn * 16 + l16;                                          \
    _Pragma("unroll") for (int kk = 0; kk < 2; ++kk)                          \
      boff[fn][kk] = 16384 + r * 128 + ((kk * 64 + lg * 16) ^ xm);            \
  }                                                                           \
  f32x4 z4 = {0.f, 0.f, 0.f, 0.f};                                            \
  f32x4 acc[4][2];                                                            \
  _Pragma("unroll") for (int a = 0; a < 4; ++a)                               \
    _Pragma("unroll") for (int b = 0; b < 2; ++b) acc[a][b] = z4;

#define GEMM_PIPELINE(NK)                                                     \
  STAGE(0, smem);                                                             \
  for (int kt = 0; kt < (NK) - 1; ++kt) {                                     \
    STAGE((size_t)(kt + 1) * 128, smem + ((kt + 1) & 1) * BUFSZ);             \
    WAITB(4);                                                                 \
    COMPUTE(smem + (kt & 1) * BUFSZ);                                         \
    __builtin_amdgcn_s_barrier();                                             \
    asm volatile("" ::: "memory");                                            \
  }                                                                           \
  WAITB(0);                                                                   \
  COMPUTE(smem + (((NK) - 1) & 1) * BUFSZ);

// ---------------------------------------------------------------------------
// Fused GEMM + LSTM cell. C = A[1024,K] @ BT[2048,K]^T, gate-interleaved N.
// Grid 128 blocks (8 m x 16 n via XCD swizzle) -> 2 blocks/CU, 4 waves/SIMD.
// ---------------------------------------------------------------------------
template<bool HEADS>
__global__ void __launch_bounds__(512, 4)
lstm_gemm(const char* __restrict__ Ab, const char* __restrict__ Bb,
          int kb, int nk, const float* __restrict__ bias,
          float* __restrict__ c_state,
          __hip_bfloat16* __restrict__ hd0, int ld0,
          const float* __restrict__ w_ang, const float* __restrict__ w_wid,
          float* __restrict__ partial) {
  __shared__ char smem[2 * BUFSZ];  // 64KB; epilogue reuses all as f32[128][128]
  const int tid = threadIdx.x;
  const int l = blockIdx.x;              // 128 blocks, XCD-swizzled
  const int xcd = l & 7, bi = l >> 3;
  const int n0 = ((xcd << 1) | (bi & 1)) * 128;
  const int m0 = (bi >> 1) * 128;

  GEMM_SETUP(Ab, kb, Bb, kb)
  GEMM_PIPELINE(nk)

  // ---- epilogue: recombine gates in LDS, apply LSTM cell
  __syncthreads();
  float* gsm = (float*)smem;  // [128][128]
#pragma unroll
  for (int fm = 0; fm < 4; ++fm)
#pragma unroll
    for (int fn = 0; fn < 2; ++fn) {
      int col = wc * 32 + fn * 16 + l16;
#pragma unroll
      for (int j = 0; j < 4; ++j)
        gsm[(wr * 64 + fm * 16 + lg * 4 + j) * 128 + col] = acc[fm][fn][j];
    }
  __syncthreads();
#pragma unroll
  for (int i = 0; i < 8; ++i) {
    int p = tid + i * 512;            // 4096 = 128 rows x 32 units
    int unit = p & 31, row = p >> 5;
    f32x4 g = *(const f32x4*)(gsm + row * 128 + unit * 4);
    f32x4 bb = *(const f32x4*)(bias + n0 + unit * 4);
    float ig = sigf(g.x + bb.x);
    float fg = sigf(g.y + bb.y);
    float gg = tanhf(g.z + bb.z);
    float og = sigf(g.w + bb.w);
    int grow = m0 + row, gu = (n0 >> 2) + unit;
    float cold = c_state[grow * RNN + gu];
    float cn = fg * cold + ig * gg;
    c_state[grow * RNN + gu] = cn;
    float h = og * tanhf(cn);
    hd0[(size_t)grow * ld0 + gu] = __float2bfloat16(h);
    if (HEADS) {
      // partial head dots: 32 consecutive tids share this row
      float pa = h * w_ang[gu], pw = h * w_wid[gu];
#pragma unroll
      for (int m = 1; m < 32; m <<= 1) {
        pa += __shfl_xor(pa, m);
        pw += __shfl_xor(pw, m);
      }
      if ((tid & 31) == 0) {
        float* pp = partial + ((size_t)(n0 >> 7) * 1024 + grow) * 2;
        pp[0] = pa; pp[1] = pw;
      }
    }
  }
}

// ---------------------------------------------------------------------------
// K3: att = sigmoid(h2 @ WoT^T); xbuf[:, :2048] = idea*att.
// Also: h1 strip copy (spread over all 128 blocks, 8KB each) and, for the 8
// n0==0 blocks, finalize heads from K2's partials -> out[b,t,:].
// ---------------------------------------------------------------------------
__global__ void __launch_bounds__(512, 4)
att_gemm(const char* __restrict__ Ab, int akb,      // h2 region, row stride bytes
         const char* __restrict__ Bb, int bkb,      // WoT
         const float* __restrict__ bo,
         const __hip_bfloat16* __restrict__ idea_bf,
         __hip_bfloat16* __restrict__ xbuf,
         const char* __restrict__ h1src,            // hbuf[t&1] (h1 cols 0..511)
         const float* __restrict__ partial,
         const float* __restrict__ b_ang, const float* __restrict__ b_wid,
         float* __restrict__ out, int t) {
  __shared__ char smem[2 * BUFSZ];
  const int tid = threadIdx.x;
  const int l = blockIdx.x;
  const int xcd = l & 7, bi = l >> 3;
  const int n0 = ((xcd << 1) | (bi & 1)) * 128;
  const int m0 = (bi >> 1) * 128;
  const int j16 = n0 >> 7;

  // h1 strip copy for next step's K1 input: rows m0..m0+127, 64B of cols each
  {
    int row = m0 + (tid >> 2), cb = (tid & 3) * 16;
    *(f32x4*)((char*)xbuf + (size_t)row * (K1K * 2) + CODE * 2 + j16 * 64 + cb) =
        *(const f32x4*)(h1src + (size_t)row * 2048 + j16 * 64 + cb);
  }

  GEMM_SETUP(Ab, akb, Bb, bkb)
  const int nk = K3K / 64;  // 8
  GEMM_PIPELINE(nk)

  // per-lane epilogue: all cols are att
#pragma unroll
  for (int fn = 0; fn < 2; ++fn) {
    int col = n0 + wc * 32 + fn * 16 + l16;
    float bia = bo[col];
#pragma unroll
    for (int fm = 0; fm < 4; ++fm)
#pragma unroll
      for (int j = 0; j < 4; ++j) {
        int row = m0 + wr * 64 + fm * 16 + lg * 4 + j;
        float a = sigf(acc[fm][fn][j] + bia);
        float id = __bfloat162float(idea_bf[(size_t)row * CODE + col]);
        xbuf[(size_t)row * K1K + col] = __float2bfloat16(id * a);
      }
  }

  // heads finalize: 8 blocks (n0==0), 128 rows x 2 outputs each
  if (n0 == 0 && tid < 256) {
    int row = m0 + (tid >> 1), g = tid & 1;
    float s = g ? b_wid[0] : b_ang[0];
#pragma unroll
    for (int j = 0; j < 16; ++j) s += partial[((size_t)j * 1024 + row) * 2 + g];
    out[(size_t)row * (TSTEPS * 2) + t * 2 + g] = g ? sigf(s) : tanhf(s);
  }
}

// ---------------------------------------------------------------------------
extern "C" void kernel_launch(void* const* d_in, const int* in_sizes, int n_in,
                              void* d_out, int out_size, void* d_ws, size_t ws_size,
                              hipStream_t stream) {
  const float* latent = (const float*)d_in[0];
  const float* w_unp  = (const float*)d_in[2];
  const float* b_unp  = (const float*)d_in[3];
  const float* w_ih1  = (const float*)d_in[4];
  const float* w_hh1  = (const float*)d_in[5];
  const float* b_ih1  = (const float*)d_in[6];
  const float* b_hh1  = (const float*)d_in[7];
  const float* w_ih2  = (const float*)d_in[8];
  const float* w_hh2  = (const float*)d_in[9];
  const float* b_ih2  = (const float*)d_in[10];
  const float* b_hh2  = (const float*)d_in[11];
  const float* w_att  = (const float*)d_in[12];
  const float* b_att  = (const float*)d_in[13];
  const float* w_wid  = (const float*)d_in[14];
  const float* b_wid  = (const float*)d_in[15];
  const float* w_ang  = (const float*)d_in[16];
  const float* b_ang  = (const float*)d_in[17];
  float* out = (float*)d_out;

  char* ws = (char*)d_ws;
  __hip_bfloat16* W1T  = (__hip_bfloat16*)(ws + 0);          // 2048 x 2560
  __hip_bfloat16* W2T  = (__hip_bfloat16*)(ws + 10485760);   // 2048 x 1024
  __hip_bfloat16* WoT  = (__hip_bfloat16*)(ws + 14680064);   // 2048 x 512
  float* b1p           = (float*)(ws + 16777216);            // 2048
  float* b2p           = (float*)(ws + 16785408);            // 2048
  float* bo            = (float*)(ws + 16793600);            // 2048
  __hip_bfloat16* idea = (__hip_bfloat16*)(ws + 16801792);   // 1024 x 2048
  __hip_bfloat16* xbuf = (__hip_bfloat16*)(ws + 20996096);   // 1024 x 2560 [idea*att | h1]
  __hip_bfloat16* hb0  = (__hip_bfloat16*)(ws + 26238976);   // 1024 x 1024 [h1|h2]
  float* c1            = (float*)(ws + 28336128);            // 1024 x 512
  float* c2            = (float*)(ws + 30433280);            // 1024 x 512
  __hip_bfloat16* hb1  = (__hip_bfloat16*)(ws + 32530432);   // 1024 x 1024
  float* partial       = (float*)(ws + 34627584);            // 16 x 1024 x 2

  __hip_bfloat16* hbuf[2] = {hb0, hb1};

  conv_w1<<<2048, 256, 0, stream>>>(w_ih1, w_hh1, W1T);
  conv_w2<<<2048, 256, 0, stream>>>(w_ih2, w_hh2, W2T);
  conv_wo<<<2048, 256, 0, stream>>>(w_att, WoT);
  conv_b<<<8, 256, 0, stream>>>(b_ih1, b_hh1, b_ih2, b_hh2, b_att, b1p, b2p, bo);
  init_zero<<<1024, 256, 0, stream>>>(ws + 26238976, (char*)xbuf);
  idea_kernel<<<8192, 256, 0, stream>>>(latent, w_unp, b_unp, idea, xbuf);

  for (int t = 0; t < TSTEPS; ++t) {
    __hip_bfloat16* hc = hbuf[t & 1];        // [h1(t) | h2(t-1)] for K2
    __hip_bfloat16* hn = hbuf[(t + 1) & 1];  // next-step buffer
    // K1: gates1 = xbuf @ W1 ; cell -> c1, h1 -> hc[:,0:512]
    lstm_gemm<false><<<128, 512, 0, stream>>>(
        (const char*)xbuf, (const char*)W1T, K1K * 2, K1K / 64, b1p, c1,
        hc, 1024, nullptr, nullptr, nullptr);
    // K2: gates2 = hc @ W2 ; cell -> c2, h2 -> hn[:,512:1024]; head partials
    lstm_gemm<true><<<128, 512, 0, stream>>>(
        (const char*)hc, (const char*)W2T, K2K * 2, K2K / 64, b2p, c2,
        hn + RNN, 1024, w_ang, w_wid, partial);
    // K3: att from h2 (hn cols 512:1024); writes xbuf[:, :2048]; h1 strip copy
    // (hc cols 0:512 -> xbuf cols 2048:2560); heads finalize -> out
    att_gemm<<<128, 512, 0, stream>>>(
        (const char*)hn + 1024, 2048, (const char*)WoT, 1024,
        bo, idea, xbuf, (const char*)hc, partial, b_ang, b_wid, out, t);
  }
}

// Round 10
// 5069.925 us; speedup vs baseline: 2.6248x; 1.4259x over previous
//
#include <hip/hip_runtime.h>
#include <hip/hip_bf16.h>
#include <cmath>

typedef __attribute__((ext_vector_type(8))) short bf16x8;
typedef __attribute__((ext_vector_type(4))) float f32x4;
typedef unsigned int u32;

#define DEVI __device__ __forceinline__

DEVI float sigf(float x) { return 1.0f / (1.0f + __expf(-x)); }

// async global->LDS, 16B per lane. LDS dest must be wave-uniform base (HW adds lane*16).
typedef const __attribute__((address_space(1))) u32* gas_t;
typedef __attribute__((address_space(3))) u32* las_t;
DEVI void g2l16(const void* g, void* l) {
  __builtin_amdgcn_global_load_lds((gas_t)g, (las_t)l, 16, 0, 0);
}

// ---- problem constants
#define BATCH 1024
#define CODE  2048
#define RNN   512
#define NG    2048      // 4*RNN
#define TSTEPS 128
#define K1K   2560      // CODE + RNN
#define K2K   1024
#define K3K   512

#define BUFSZ 16384     // one BK=64 tile: A[64][128B] + B[64][128B]

// ---------------------------------------------------------------------------
// prologue kernels (run every launch; d_ws is re-poisoned before each launch)
// ---------------------------------------------------------------------------

__global__ void conv_w1(const float* __restrict__ w_ih1, const float* __restrict__ w_hh1,
                        __hip_bfloat16* __restrict__ W1T) {
  int np = blockIdx.x;                       // 0..2047, gate-interleaved: np = 4u+g
  int co = (np & 3) * RNN + (np >> 2);       // original gate column
  for (int k = threadIdx.x; k < K1K; k += 256) {
    float v = (k < CODE) ? w_ih1[(size_t)k * NG + co]
                         : w_hh1[(size_t)(k - CODE) * NG + co];
    W1T[(size_t)np * K1K + k] = __float2bfloat16(v);
  }
}

__global__ void conv_w2(const float* __restrict__ w_ih2, const float* __restrict__ w_hh2,
                        __hip_bfloat16* __restrict__ W2T) {
  int np = blockIdx.x;
  int co = (np & 3) * RNN + (np >> 2);
  for (int k = threadIdx.x; k < K2K; k += 256) {
    float v = (k < RNN) ? w_ih2[(size_t)k * NG + co]
                        : w_hh2[(size_t)(k - RNN) * NG + co];
    W2T[(size_t)np * K2K + k] = __float2bfloat16(v);
  }
}

// WoT[n][k], n<2048 (att only; heads handled separately)
__global__ void conv_wo(const float* __restrict__ w_att, __hip_bfloat16* __restrict__ WoT) {
  int n = blockIdx.x;  // 0..2047
  for (int k = threadIdx.x; k < K3K; k += 256)
    WoT[(size_t)n * K3K + k] = __float2bfloat16(w_att[(size_t)k * CODE + n]);
}

__global__ void conv_b(const float* b_ih1, const float* b_hh1,
                       const float* b_ih2, const float* b_hh2,
                       const float* b_att,
                       float* b1p, float* b2p, float* bo) {
  int i = blockIdx.x * 256 + threadIdx.x;
  if (i < NG) {
    int co = (i & 3) * RNN + (i >> 2);
    b1p[i] = b_ih1[co] + b_hh1[co];
    b2p[i] = b_ih2[co] + b_hh2[co];
    bo[i] = b_att[i];   // natural order, i < 2048 == NG
  }
}

// zero hbuf0(2MB)+c1(2MB)+c2(2MB) contiguous + the h1 strip of xbuf
__global__ void init_zero(char* __restrict__ zb, char* __restrict__ xb) {
  int idx = blockIdx.x * 256 + threadIdx.x;       // 262144 threads
  f32x4 z = {0.f, 0.f, 0.f, 0.f};
  for (int i = idx; i < 393216; i += 262144) *(f32x4*)(zb + (size_t)i * 16) = z;
  for (int i = idx; i < 65536; i += 262144) {
    int row = i >> 6, j = i & 63;
    *(f32x4*)(xb + (size_t)row * (K1K * 2) + CODE * 2 + (size_t)j * 16) = z;
  }
}

// idea = tanh(latent @ w_unpack + b); also xbuf[:,0:2048] = idea (att0 = 1)
__global__ void idea_kernel(const float* __restrict__ latent, const float* __restrict__ w,
                            const float* __restrict__ b,
                            __hip_bfloat16* __restrict__ idea_bf,
                            __hip_bfloat16* __restrict__ x_bf) {
  int idx = blockIdx.x * 256 + threadIdx.x;       // 2M = 1024*2048
  int bi = idx >> 11, j = idx & 2047;
  const float* lr = latent + bi * 128;
  float s = b[j];
#pragma unroll 8
  for (int k = 0; k < 128; ++k) s = fmaf(lr[k], w[(size_t)k * CODE + j], s);
  __hip_bfloat16 h = __float2bfloat16(tanhf(s));
  idea_bf[idx] = h;
  x_bf[(size_t)bi * K1K + j] = h;
}

// ---- shared GEMM inner-loop fragments --------------------------------------
// BM=64, BN=64, BK=64; 256 threads = 4 waves (2x2), wave tile 32x32.
// Grid 512 = 2 independent blocks/CU: one block's barrier stalls are covered
// by the other block's MFMA issue (cross-block co-scheduling).
// LDS buffer: A[64][128B] @0, B[64][128B] @8192 (linear; involution:
// LDS[r*128+q] holds global (r, q ^ ((r&7)<<4))). 16 1KB chunks, 4/wave.
// 3 buffers, depth-2 prefetch, counted s_waitcnt vmcnt(4) + raw s_barrier.

#define STAGE(KO, DST)                                                        \
  _Pragma("unroll") for (int j = 0; j < 4; ++j)                               \
      g2l16(gp[j] + (KO), (DST) + ldsc[j]);

#define COMPUTE(SB)                                                           \
  __builtin_amdgcn_s_setprio(1);                                              \
  _Pragma("unroll") for (int kk = 0; kk < 2; ++kk) {                          \
    bf16x8 av[2], bv[2];                                                      \
    _Pragma("unroll") for (int fm = 0; fm < 2; ++fm)                          \
        av[fm] = *(const bf16x8*)((SB) + aoff[fm][kk]);                       \
    _Pragma("unroll") for (int fn = 0; fn < 2; ++fn)                          \
        bv[fn] = *(const bf16x8*)((SB) + boff[fn][kk]);                       \
    _Pragma("unroll") for (int fm = 0; fm < 2; ++fm)                          \
      _Pragma("unroll") for (int fn = 0; fn < 2; ++fn)                        \
        acc[fm][fn] = __builtin_amdgcn_mfma_f32_16x16x32_bf16(                \
            av[fm], bv[fn], acc[fm][fn], 0, 0, 0);                            \
  }                                                                           \
  __builtin_amdgcn_s_setprio(0);

#define WAITB(N)                                                              \
  asm volatile("s_waitcnt vmcnt(" #N ")" ::: "memory");                       \
  __builtin_amdgcn_s_barrier();                                               \
  asm volatile("" ::: "memory");

#define GEMM_SETUP(AB, AKB, BB, BKB)                                          \
  const int lane = tid & 63, wv = tid >> 6;                                   \
  const int rl = lane >> 3;                                                   \
  const int cswz = ((lane & 7) * 16) ^ (rl << 4);                             \
  const char* gp[4]; int ldsc[4];                                             \
  _Pragma("unroll") for (int j = 0; j < 4; ++j) {                             \
    int c = wv * 4 + j;                                                       \
    int row = (c < 8) ? (m0 + c * 8 + rl) : (n0 + (c - 8) * 8 + rl);          \
    gp[j] = ((c < 8) ? (AB) : (BB)) +                                         \
            (size_t)row * ((c < 8) ? (AKB) : (BKB)) + cswz;                   \
    ldsc[j] = c * 1024;                                                       \
  }                                                                           \
  const int l16 = lane & 15, lg = lane >> 4;                                  \
  const int wr = wv & 1, wc = wv >> 1;                                        \
  const int xm = (l16 & 7) << 4;                                              \
  int aoff[2][2], boff[2][2];                                                 \
  _Pragma("unroll") for (int fm = 0; fm < 2; ++fm) {                          \
    int r = wr * 32 + fm * 16 + l16;                                          \
    _Pragma("unroll") for (int kk = 0; kk < 2; ++kk)                          \
      aoff[fm][kk] = r * 128 + ((kk * 64 + lg * 16) ^ xm);                    \
  }                                                                           \
  _Pragma("unroll") for (int fn = 0; fn < 2; ++fn) {                          \
    int r = wc * 32 + fn * 16 + l16;                                          \
    _Pragma("unroll") for (int kk = 0; kk < 2; ++kk)                          \
      boff[fn][kk] = 8192 + r * 128 + ((kk * 64 + lg * 16) ^ xm);             \
  }                                                                           \
  f32x4 z4 = {0.f, 0.f, 0.f, 0.f};                                            \
  f32x4 acc[2][2];                                                            \
  _Pragma("unroll") for (int a = 0; a < 2; ++a)                               \
    _Pragma("unroll") for (int b = 0; b < 2; ++b) acc[a][b] = z4;

#define GEMM_PIPELINE(NK)                                                     \
  STAGE(0, smem);                                                             \
  STAGE(128, smem + BUFSZ);                                                   \
  for (int kt = 0; kt < (NK) - 1; ++kt) {                                     \
    WAITB(4);                                                                 \
    if (kt + 2 < (NK)) {                                                      \
      char* nb = smem + ((kt + 2) % 3) * BUFSZ;                               \
      STAGE((size_t)(kt + 2) * 128, nb);                                      \
    }                                                                         \
    const char* sb = smem + (kt % 3) * BUFSZ;                                 \
    COMPUTE(sb);                                                              \
  }                                                                           \
  WAITB(0);                                                                   \
  COMPUTE(smem + (((NK) - 1) % 3) * BUFSZ);

// ---------------------------------------------------------------------------
// Fused GEMM + LSTM cell. C = A[1024,K] @ BT[2048,K]^T, gate-interleaved N.
// Grid 512 (16 m x 32 n via XCD swizzle), 256 threads, 2 blocks/CU.
// ---------------------------------------------------------------------------
template<bool HEADS>
__global__ void __launch_bounds__(256, 2)
lstm_gemm(const char* __restrict__ Ab, const char* __restrict__ Bb,
          int kb, int nk, const float* __restrict__ bias,
          float* __restrict__ c_state,
          __hip_bfloat16* __restrict__ hd0, int ld0,
          const float* __restrict__ w_ang, const float* __restrict__ w_wid,
          float* __restrict__ partial) {
  __shared__ char smem[3 * BUFSZ];  // 48KB; epilogue reuses 17.4KB as f32[64][68]
  const int tid = threadIdx.x;
  const int l = blockIdx.x;              // 512 blocks, XCD-swizzled
  const int xcd = l & 7, bi = l >> 3;    // bi 0..63
  const int n0 = (xcd * 4 + (bi & 3)) * 64;
  const int m0 = (bi >> 2) * 64;

  GEMM_SETUP(Ab, kb, Bb, kb)
  GEMM_PIPELINE(nk)

  // ---- epilogue: recombine gates in LDS, apply LSTM cell
  __syncthreads();
  float* gsm = (float*)smem;  // [64][68]
#pragma unroll
  for (int fm = 0; fm < 2; ++fm)
#pragma unroll
    for (int fn = 0; fn < 2; ++fn) {
      int col = wc * 32 + fn * 16 + l16;
#pragma unroll
      for (int j = 0; j < 4; ++j)
        gsm[(wr * 32 + fm * 16 + lg * 4 + j) * 68 + col] = acc[fm][fn][j];
    }
  __syncthreads();
#pragma unroll
  for (int i = 0; i < 4; ++i) {
    int p = tid + i * 256;            // 1024 = 64 rows x 16 units
    int unit = p & 15, row = p >> 4;
    f32x4 g = *(const f32x4*)(gsm + row * 68 + unit * 4);
    f32x4 bb = *(const f32x4*)(bias + n0 + unit * 4);
    float ig = sigf(g.x + bb.x);
    float fg = sigf(g.y + bb.y);
    float gg = tanhf(g.z + bb.z);
    float og = sigf(g.w + bb.w);
    int grow = m0 + row, gu = (n0 >> 2) + unit;
    float cold = c_state[grow * RNN + gu];
    float cn = fg * cold + ig * gg;
    c_state[grow * RNN + gu] = cn;
    float h = og * tanhf(cn);
    hd0[(size_t)grow * ld0 + gu] = __float2bfloat16(h);
    if (HEADS) {
      // partial head dots: 16 consecutive tids share this row
      float pa = h * w_ang[gu], pw = h * w_wid[gu];
#pragma unroll
      for (int m = 1; m < 16; m <<= 1) {
        pa += __shfl_xor(pa, m);
        pw += __shfl_xor(pw, m);
      }
      if ((tid & 15) == 0) {
        float* pp = partial + ((size_t)(n0 >> 6) * 1024 + grow) * 2;
        pp[0] = pa; pp[1] = pw;
      }
    }
  }
}

// ---------------------------------------------------------------------------
// K3: att = sigmoid(h2 @ WoT^T); xbuf[:, :2048] = idea*att.
// Also: h1 strip copy (spread over all 512 blocks, 2KB each) and, for the 16
// n0==0 blocks, finalize heads from K2's partials -> out[b,t,:].
// ---------------------------------------------------------------------------
__global__ void __launch_bounds__(256, 2)
att_gemm(const char* __restrict__ Ab, int akb,      // h2 region, row stride bytes
         const char* __restrict__ Bb, int bkb,      // WoT
         const float* __restrict__ bo,
         const __hip_bfloat16* __restrict__ idea_bf,
         __hip_bfloat16* __restrict__ xbuf,
         const char* __restrict__ h1src,            // hbuf[t&1] (h1 cols 0..511)
         const float* __restrict__ partial,
         const float* __restrict__ b_ang, const float* __restrict__ b_wid,
         float* __restrict__ out, int t) {
  __shared__ char smem[3 * BUFSZ];
  const int tid = threadIdx.x;
  const int l = blockIdx.x;
  const int xcd = l & 7, bi = l >> 3;
  const int n0 = (xcd * 4 + (bi & 3)) * 64;
  const int m0 = (bi >> 2) * 64;
  const int j16 = n0 >> 6;               // 0..31, 32B of the h1 strip per block

  // h1 strip copy for next step's K1 input: rows m0..m0+63, 32B of cols each
  if (tid < 128) {
    int row = m0 + (tid >> 1), cb = (tid & 1) * 16;
    *(f32x4*)((char*)xbuf + (size_t)row * (K1K * 2) + CODE * 2 + j16 * 32 + cb) =
        *(const f32x4*)(h1src + (size_t)row * 2048 + j16 * 32 + cb);
  }

  GEMM_SETUP(Ab, akb, Bb, bkb)
  const int nk = K3K / 64;  // 8
  GEMM_PIPELINE(nk)

  // per-lane epilogue: all cols are att
#pragma unroll
  for (int fn = 0; fn < 2; ++fn) {
    int col = n0 + wc * 32 + fn * 16 + l16;
    float bia = bo[col];
#pragma unroll
    for (int fm = 0; fm < 2; ++fm)
#pragma unroll
      for (int j = 0; j < 4; ++j) {
        int row = m0 + wr * 32 + fm * 16 + lg * 4 + j;
        float a = sigf(acc[fm][fn][j] + bia);
        float id = __bfloat162float(idea_bf[(size_t)row * CODE + col]);
        xbuf[(size_t)row * K1K + col] = __float2bfloat16(id * a);
      }
  }

  // heads finalize: 16 blocks (n0==0), 64 rows x 2 outputs each
  if (n0 == 0 && tid < 128) {
    int row = m0 + (tid >> 1), g = tid & 1;
    float s = g ? b_wid[0] : b_ang[0];
#pragma unroll
    for (int j = 0; j < 32; ++j) s += partial[((size_t)j * 1024 + row) * 2 + g];
    out[(size_t)row * (TSTEPS * 2) + t * 2 + g] = g ? sigf(s) : tanhf(s);
  }
}

// ---------------------------------------------------------------------------
extern "C" void kernel_launch(void* const* d_in, const int* in_sizes, int n_in,
                              void* d_out, int out_size, void* d_ws, size_t ws_size,
                              hipStream_t stream) {
  const float* latent = (const float*)d_in[0];
  const float* w_unp  = (const float*)d_in[2];
  const float* b_unp  = (const float*)d_in[3];
  const float* w_ih1  = (const float*)d_in[4];
  const float* w_hh1  = (const float*)d_in[5];
  const float* b_ih1  = (const float*)d_in[6];
  const float* b_hh1  = (const float*)d_in[7];
  const float* w_ih2  = (const float*)d_in[8];
  const float* w_hh2  = (const float*)d_in[9];
  const float* b_ih2  = (const float*)d_in[10];
  const float* b_hh2  = (const float*)d_in[11];
  const float* w_att  = (const float*)d_in[12];
  const float* b_att  = (const float*)d_in[13];
  const float* w_wid  = (const float*)d_in[14];
  const float* b_wid  = (const float*)d_in[15];
  const float* w_ang  = (const float*)d_in[16];
  const float* b_ang  = (const float*)d_in[17];
  float* out = (float*)d_out;

  char* ws = (char*)d_ws;
  __hip_bfloat16* W1T  = (__hip_bfloat16*)(ws + 0);          // 2048 x 2560
  __hip_bfloat16* W2T  = (__hip_bfloat16*)(ws + 10485760);   // 2048 x 1024
  __hip_bfloat16* WoT  = (__hip_bfloat16*)(ws + 14680064);   // 2048 x 512
  float* b1p           = (float*)(ws + 16777216);            // 2048
  float* b2p           = (float*)(ws + 16785408);            // 2048
  float* bo            = (float*)(ws + 16793600);            // 2048
  __hip_bfloat16* idea = (__hip_bfloat16*)(ws + 16801792);   // 1024 x 2048
  __hip_bfloat16* xbuf = (__hip_bfloat16*)(ws + 20996096);   // 1024 x 2560 [idea*att | h1]
  __hip_bfloat16* hb0  = (__hip_bfloat16*)(ws + 26238976);   // 1024 x 1024 [h1|h2]
  float* c1            = (float*)(ws + 28336128);            // 1024 x 512
  float* c2            = (float*)(ws + 30433280);            // 1024 x 512
  __hip_bfloat16* hb1  = (__hip_bfloat16*)(ws + 32530432);   // 1024 x 1024
  float* partial       = (float*)(ws + 34627584);            // 32 x 1024 x 2

  __hip_bfloat16* hbuf[2] = {hb0, hb1};

  conv_w1<<<2048, 256, 0, stream>>>(w_ih1, w_hh1, W1T);
  conv_w2<<<2048, 256, 0, stream>>>(w_ih2, w_hh2, W2T);
  conv_wo<<<2048, 256, 0, stream>>>(w_att, WoT);
  conv_b<<<8, 256, 0, stream>>>(b_ih1, b_hh1, b_ih2, b_hh2, b_att, b1p, b2p, bo);
  init_zero<<<1024, 256, 0, stream>>>(ws + 26238976, (char*)xbuf);
  idea_kernel<<<8192, 256, 0, stream>>>(latent, w_unp, b_unp, idea, xbuf);

  for (int t = 0; t < TSTEPS; ++t) {
    __hip_bfloat16* hc = hbuf[t & 1];        // [h1(t) | h2(t-1)] for K2
    __hip_bfloat16* hn = hbuf[(t + 1) & 1];  // next-step buffer
    // K1: gates1 = xbuf @ W1 ; cell -> c1, h1 -> hc[:,0:512]
    lstm_gemm<false><<<512, 256, 0, stream>>>(
        (const char*)xbuf, (const char*)W1T, K1K * 2, K1K / 64, b1p, c1,
        hc, 1024, nullptr, nullptr, nullptr);
    // K2: gates2 = hc @ W2 ; cell -> c2, h2 -> hn[:,512:1024]; head partials
    lstm_gemm<true><<<512, 256, 0, stream>>>(
        (const char*)hc, (const char*)W2T, K2K * 2, K2K / 64, b2p, c2,
        hn + RNN, 1024, w_ang, w_wid, partial);
    // K3: att from h2 (hn cols 512:1024); writes xbuf[:, :2048]; h1 strip copy
    // (hc cols 0:512 -> xbuf cols 2048:2560); heads finalize -> out
    att_gemm<<<512, 256, 0, stream>>>(
        (const char*)hn + 1024, 2048, (const char*)WoT, 1024,
        bo, idea, xbuf, (const char*)hc, partial, b_ang, b_wid, out, t);
  }
}